// Round 18
// baseline (452.798 us; speedup 1.0000x reference)
//
#include <hip/hip_runtime.h>

#define NNODES 100000
#define NEDGES 1600000
#define FIN 128
#define FH 64
#define FOUT 32
#define NGRAPH 128
#define EPSV 1e-5f

#define NBLK ((NNODES + 255) / 256)  // 391
#define GM ((NNODES + 63) / 64)      // 1563 gemm blocks
#define FILLBLK 2048

typedef unsigned short ushort_t;
typedef __attribute__((ext_vector_type(8))) short bf16x8;
typedef __attribute__((ext_vector_type(4))) float f32x4;

// ---- bf16 helpers (RNE) ----
__device__ inline unsigned f2bf(float f) {
  union { float f; unsigned u; } x;
  x.f = f;
  return (x.u + 0x7fffu + ((x.u >> 16) & 1u)) >> 16;
}
__device__ inline float bflo(unsigned u) {
  union { unsigned u; float f; } x;
  x.u = u << 16;
  return x.f;
}
__device__ inline float bfhi(unsigned u) {
  union { unsigned u; float f; } x;
  x.u = u & 0xffff0000u;
  return x.f;
}

// ---------------- degree accumulation (XCD-partitioned) ----------------

__global__ void k_deg_accum(const int* __restrict__ dst, int* __restrict__ deg) {
  const int SLICE = NNODES / 8;
  int xcd = blockIdx.x & 7;
  int lo = xcd * SLICE, hi = lo + SLICE;
  int chunk = blockIdx.x >> 3;
  int nchunk = gridDim.x >> 3;
  for (int i = chunk * blockDim.x + threadIdx.x; i < NEDGES; i += nchunk * blockDim.x) {
    int d = dst[i];
    if (d >= lo && d < hi) atomicAdd(&deg[d], 1);
  }
}

// ---------------- one-kernel CSR offsets: block scan + atomic global base ---

__global__ void k_scan_atomic(const int* __restrict__ deg, int* __restrict__ gtotal,
                              int* __restrict__ off, float* __restrict__ dis) {
  __shared__ int ls[256];
  __shared__ int sbase;
  int b = blockIdx.x, t = threadIdx.x;
  int i = b * 256 + t;
  int v = (i < NNODES) ? deg[i] : 0;
  ls[t] = v;
  __syncthreads();
  for (int s = 1; s < 256; s <<= 1) {
    int add = (t >= s) ? ls[t - s] : 0;
    __syncthreads();
    ls[t] += add;
    __syncthreads();
  }
  if (t == 255) sbase = atomicAdd(gtotal, ls[255]);
  __syncthreads();
  if (i < NNODES) {
    off[i] = sbase + ls[t] - v;        // exclusive within block + atomic base
    dis[i] = rsqrtf((float)v + 1.0f);  // self-loop folded in
  }
}

// ---------------- MFMA GEMM body (A fp32; BN fused for layer 2) -------------

template <int K, bool BN>
__device__ __forceinline__ void gemm_body(int bid, const float* __restrict__ A,
                                          const float* __restrict__ W,
                                          const float* __restrict__ stats,
                                          const float* __restrict__ gamma,
                                          const float* __restrict__ beta,
                                          const float* __restrict__ dis,
                                          ushort_t* __restrict__ out, ushort_t* wt,
                                          float* bn_sc, float* bn_sh) {
  const int WT = K + 8;
  if (BN && threadIdx.x < K) {
    int f = threadIdx.x;
    float mean = stats[f] * (1.0f / NNODES);
    float var = stats[K + f] * (1.0f / NNODES) - mean * mean;
    float s = gamma[f] * rsqrtf(var + EPSV);
    bn_sc[f] = s;
    bn_sh[f] = beta[f] - mean * s;  // bias b cancels in training-mode BN
  }
  for (int idx = threadIdx.x; idx < K * 64; idx += 256) {
    int k = idx >> 6, col = idx & 63;
    wt[col * WT + k] = (ushort_t)f2bf(W[idx]);
  }
  __syncthreads();

  int wave = threadIdx.x >> 6;
  int lane = threadIdx.x & 63;
  int rrow = lane & 15;
  int g = lane >> 4;
  int row0 = (bid * 4 + wave) * 16;
  int arow = min(row0 + rrow, NNODES - 1);
  const float* a = A + (long long)arow * K;

  f32x4 acc0 = {0.f, 0.f, 0.f, 0.f}, acc1 = acc0, acc2 = acc0, acc3 = acc0;

#pragma unroll
  for (int ks = 0; ks < K / 32; ++ks) {
    int koff = ks * 32 + g * 8;
    f32x4 xa = __builtin_nontemporal_load((const f32x4*)(a + koff));
    f32x4 xb = __builtin_nontemporal_load((const f32x4*)(a + koff + 4));
    float xs[8] = {xa.x, xa.y, xa.z, xa.w, xb.x, xb.y, xb.z, xb.w};
    if (BN) {
#pragma unroll
      for (int j = 0; j < 8; ++j)
        xs[j] = fmaxf(fmaf(xs[j], bn_sc[koff + j], bn_sh[koff + j]), 0.0f);
    }
    bf16x8 af;
#pragma unroll
    for (int j = 0; j < 8; ++j) af[j] = (short)f2bf(xs[j]);
    bf16x8 b0 = *(const bf16x8*)&wt[(0 * 16 + rrow) * WT + koff];
    bf16x8 b1 = *(const bf16x8*)&wt[(1 * 16 + rrow) * WT + koff];
    bf16x8 b2 = *(const bf16x8*)&wt[(2 * 16 + rrow) * WT + koff];
    bf16x8 b3 = *(const bf16x8*)&wt[(3 * 16 + rrow) * WT + koff];
    acc0 = __builtin_amdgcn_mfma_f32_16x16x32_bf16(af, b0, acc0, 0, 0, 0);
    acc1 = __builtin_amdgcn_mfma_f32_16x16x32_bf16(af, b1, acc1, 0, 0, 0);
    acc2 = __builtin_amdgcn_mfma_f32_16x16x32_bf16(af, b2, acc2, 0, 0, 0);
    acc3 = __builtin_amdgcn_mfma_f32_16x16x32_bf16(af, b3, acc3, 0, 0, 0);
  }

  int orow0 = row0 + g * 4;
#pragma unroll
  for (int r = 0; r < 4; ++r) {
    int orow = orow0 + r;
    if (orow < NNODES) {
      float d = dis[orow];
      ushort_t* o = out + (long long)orow * FH + rrow;
      o[0] = (ushort_t)f2bf(acc0[r] * d);
      o[16] = (ushort_t)f2bf(acc1[r] * d);
      o[32] = (ushort_t)f2bf(acc2[r] * d);
      o[48] = (ushort_t)f2bf(acc3[r] * d);
    }
  }
}

template <int K, bool BN>
__global__ void k_gemm_mfma(const float* __restrict__ A, const float* __restrict__ W,
                            const float* __restrict__ stats, const float* __restrict__ gamma,
                            const float* __restrict__ beta, const float* __restrict__ dis,
                            ushort_t* __restrict__ out) {
  __shared__ ushort_t wt[64 * (K + 8)];
  __shared__ float sc[K], sh[K];
  gemm_body<K, BN>(blockIdx.x, A, W, stats, gamma, beta, dis, out, wt, sc, sh);
}

// ---------------- fused: GEMM1 (blocks [0,GM)) || CSR fill (rest) -----------

__global__ void k_fill_gemm1(const float* __restrict__ x, const float* __restrict__ W1,
                             const float* __restrict__ dis, ushort_t* __restrict__ bufA,
                             const int* __restrict__ src, const int* __restrict__ dst,
                             const int* __restrict__ off, int* __restrict__ cursor,
                             int* __restrict__ csr) {
  __shared__ ushort_t wt[64 * (FIN + 8)];
  if (blockIdx.x < GM) {
    gemm_body<FIN, false>(blockIdx.x, x, W1, nullptr, nullptr, nullptr, dis, bufA, wt,
                          nullptr, nullptr);
  } else {
    int bb = blockIdx.x - GM;
    const int SLICE = NNODES / 8;
    int xcd = bb & 7;
    int lo = xcd * SLICE, hi = lo + SLICE;
    int chunk = bb >> 3;
    int nchunk = FILLBLK >> 3;
    for (int i = chunk * blockDim.x + threadIdx.x; i < NEDGES; i += nchunk * blockDim.x) {
      int d = dst[i];
      if (d >= lo && d < hi) {
        int p = atomicAdd(&cursor[d], 1);
        csr[off[d] + p] = src[i];
      }
    }
  }
}

// ---------------- aggregation (R10 structure, best measured) ----------------

#define ACC8(acc, u, ok)                       \
  acc[0] += (ok) ? bflo(u.x) : 0.0f;           \
  acc[1] += (ok) ? bfhi(u.x) : 0.0f;           \
  acc[2] += (ok) ? bflo(u.y) : 0.0f;           \
  acc[3] += (ok) ? bfhi(u.y) : 0.0f;           \
  acc[4] += (ok) ? bflo(u.z) : 0.0f;           \
  acc[5] += (ok) ? bfhi(u.z) : 0.0f;           \
  acc[6] += (ok) ? bflo(u.w) : 0.0f;           \
  acc[7] += (ok) ? bfhi(u.w) : 0.0f;

__global__ void k_gather(const ushort_t* __restrict__ hs, const int* __restrict__ csr,
                         const int* __restrict__ off, const int* __restrict__ deg,
                         const float* __restrict__ dis, float* __restrict__ out,
                         float* __restrict__ stats) {
  __shared__ float ls[2 * FH];
  int tid = threadIdx.x;
  if (tid < 2 * FH) ls[tid] = 0.0f;
  __syncthreads();
  int lane = tid & 63;
  int q = lane >> 3;  // edge-slot group 0..7
  int i = lane & 7;   // feature octet: features [8i, 8i+7]
  int wid = (blockIdx.x * blockDim.x + tid) >> 6;
  int nw = (gridDim.x * blockDim.x) >> 6;
  const int HALF = NNODES / 2;
  float s1[8], s2[8];
#pragma unroll
  for (int f = 0; f < 8; ++f) s1[f] = s2[f] = 0.0f;

  for (int p = wid; p < HALF; p += nw) {
    int dA = p, dB = p + HALF;
    int bA = off[dA], eA = bA + deg[dA];
    int bB = off[dB], eB = bB + deg[dB];
    uint4 selfA = *(const uint4*)(hs + (long long)dA * FH + i * 8);
    uint4 selfB = *(const uint4*)(hs + (long long)dB * FH + i * 8);
    float accA[8], accB[8];
#pragma unroll
    for (int f = 0; f < 8; ++f) accA[f] = accB[f] = 0.0f;
    bool q0 = (q == 0);
    ACC8(accA, selfA, q0);
    ACC8(accB, selfB, q0);

    int nA = (eA - bA + 15) >> 4, nB = (eB - bB + 15) >> 4;
    int niter = max(nA, nB);  // wave-uniform
    int lastA = max(eA - 1, 0), lastB = max(eB - 1, 0);
    int kA0 = bA + q, kA1 = bA + q + 8;
    int kB0 = bB + q, kB1 = bB + q + 8;
    for (int j = 0; j < niter; ++j) {
      int a0 = kA0 + 16 * j, a1 = kA1 + 16 * j;
      int b0 = kB0 + 16 * j, b1 = kB1 + 16 * j;
      int cA0 = csr[min(a0, lastA)];
      int cA1 = csr[min(a1, lastA)];
      int cB0 = csr[min(b0, lastB)];
      int cB1 = csr[min(b1, lastB)];
      uint4 uA0 = *(const uint4*)(hs + (long long)cA0 * FH + i * 8);
      uint4 uA1 = *(const uint4*)(hs + (long long)cA1 * FH + i * 8);
      uint4 uB0 = *(const uint4*)(hs + (long long)cB0 * FH + i * 8);
      uint4 uB1 = *(const uint4*)(hs + (long long)cB1 * FH + i * 8);
      bool A0 = a0 < eA, A1 = a1 < eA, B0 = b0 < eB, B1 = b1 < eB;
      ACC8(accA, uA0, A0);
      ACC8(accA, uA1, A1);
      ACC8(accB, uB0, B0);
      ACC8(accB, uB1, B1);
    }
    // butterfly across the 8 groups (lane bits 3,4,5)
#pragma unroll
    for (int f = 0; f < 8; ++f) {
      accA[f] += __shfl_xor(accA[f], 8);
      accA[f] += __shfl_xor(accA[f], 16);
      accA[f] += __shfl_xor(accA[f], 32);
      accB[f] += __shfl_xor(accB[f], 8);
      accB[f] += __shfl_xor(accB[f], 16);
      accB[f] += __shfl_xor(accB[f], 32);
    }
    float ddA = dis[dA], ddB = dis[dB];
#pragma unroll
    for (int f = 0; f < 8; ++f) {
      accA[f] *= ddA;
      accB[f] *= ddB;
      s1[f] += accA[f] + accB[f];
      s2[f] += accA[f] * accA[f] + accB[f] * accB[f];
    }
    if (q == 0) {
      f32x4 v0 = {accA[0], accA[1], accA[2], accA[3]};
      f32x4 v1 = {accA[4], accA[5], accA[6], accA[7]};
      *(f32x4*)(out + (long long)dA * FH + i * 8) = v0;
      *(f32x4*)(out + (long long)dA * FH + i * 8 + 4) = v1;
    } else if (q == 1) {
      f32x4 v0 = {accB[0], accB[1], accB[2], accB[3]};
      f32x4 v1 = {accB[4], accB[5], accB[6], accB[7]};
      *(f32x4*)(out + (long long)dB * FH + i * 8) = v0;
      *(f32x4*)(out + (long long)dB * FH + i * 8 + 4) = v1;
    }
  }
  if (q == 2) {  // one copy of the per-feature partial sums per wave
#pragma unroll
    for (int f = 0; f < 8; ++f) {
      atomicAdd(&ls[i * 8 + f], s1[f]);
      atomicAdd(&ls[FH + i * 8 + f], s2[f]);
    }
  }
  __syncthreads();
  if (tid < 2 * FH) atomicAdd(&stats[tid], ls[tid]);
}

// ---------------- fused pool + final: one block per graph ----------------
// batch is sorted -> binary search the graph's node range; 4 waves reduce
// (BN2+ReLU on load), LDS combine, then 32 threads compute the output row.
// No atomics, no cnt array, one dispatch instead of two.

__global__ void k_pool_final(const float* __restrict__ h, const int* __restrict__ batch,
                             const float* __restrict__ stats, const float* __restrict__ gamma,
                             const float* __restrict__ beta, const float* __restrict__ linW,
                             const float* __restrict__ linb, float* __restrict__ out) {
  __shared__ int srange[2];
  __shared__ float partial[4][FH];
  __shared__ float pooledv[FH];
  int g = blockIdx.x;
  int tid = threadIdx.x;
  if (tid < 2) {
    int target = g + tid;  // lower_bound of target
    int lo = 0, hi = NNODES;
    while (lo < hi) {
      int mid = (lo + hi) >> 1;
      if (batch[mid] < target) lo = mid + 1;
      else hi = mid;
    }
    srange[tid] = lo;
  }
  __syncthreads();
  int start = srange[0], end = srange[1];
  int lane = tid & 63;
  int wave = tid >> 6;
  float mean = stats[lane] * (1.0f / NNODES);
  float var = stats[FH + lane] * (1.0f / NNODES) - mean * mean;
  float sc = gamma[lane] * rsqrtf(var + EPSV);
  float sh = beta[lane] - mean * sc;
  float acc = 0.0f;
  for (int n = start + wave; n < end; n += 4) {
    float v = fmaf(h[(long long)n * FH + lane], sc, sh);
    acc += fmaxf(v, 0.0f);
  }
  partial[wave][lane] = acc;
  __syncthreads();
  if (tid < FH) {
    float inv = 1.0f / fmaxf((float)(end - start), 1.0f);
    pooledv[tid] =
        (partial[0][tid] + partial[1][tid] + partial[2][tid] + partial[3][tid]) * inv;
  }
  __syncthreads();
  if (tid < FOUT) {
    float acc2 = linb[tid];
#pragma unroll
    for (int k = 0; k < FH; ++k) acc2 = fmaf(pooledv[k], linW[k * FOUT + tid], acc2);
    out[g * FOUT + tid] = acc2;
  }
}

extern "C" void kernel_launch(void* const* d_in, const int* in_sizes, int n_in,
                              void* d_out, int out_size, void* d_ws, size_t ws_size,
                              hipStream_t stream) {
  const float* x = (const float*)d_in[0];
  const int* esrc = (const int*)d_in[1];
  const int* edst = (const int*)d_in[1] + NEDGES;
  const int* batch = (const int*)d_in[2];
  const float* W1 = (const float*)d_in[3];
  // d_in[4] = b1 (cancels in BN), d_in[6] = b2 (cancels in BN)
  const float* W2 = (const float*)d_in[5];
  const float* gamma = (const float*)d_in[7];
  const float* beta = (const float*)d_in[8];
  const float* linW = (const float*)d_in[9];
  const float* linb = (const float*)d_in[10];
  float* out = (float*)d_out;

  // workspace layout (bufA bf16, bufB fp32)
  ushort_t* bufA = (ushort_t*)d_ws;                        // N*64 u16
  float* bufB = (float*)(bufA + (long long)NNODES * FH);   // N*64 f32
  float* dis = bufB + (long long)NNODES * FH;              // N
  int* off = (int*)(dis + NNODES);                         // N
  int* csr = off + NNODES;                                 // E
  int* deg = csr + NEDGES;                                 // N   --- zeroed region start
  int* cursor = deg + NNODES;                              // N
  int* gtotal = cursor + NNODES;                           // 1
  float* stats1 = (float*)(gtotal + 1);                    // 128
  float* stats2 = stats1 + 2 * FH;                         // 128 --- zeroed region end

  const int BT = 256;

  hipMemsetAsync(deg, 0, (size_t)(2 * NNODES + 1 + 2 * 2 * FH) * sizeof(int), stream);

  // CSR pipeline (scan collapsed via atomic base); gemm1 fused into fill
  k_deg_accum<<<2048, BT, 0, stream>>>(edst, deg);
  k_scan_atomic<<<NBLK, BT, 0, stream>>>(deg, gtotal, off, dis);
  k_fill_gemm1<<<GM + FILLBLK, BT, 0, stream>>>(x, W1, dis, bufA, esrc, edst, off, cursor, csr);

  // layer 1 aggregation
  k_gather<<<2048, BT, 0, stream>>>(bufA, csr, off, deg, dis, bufB, stats1);

  // layer 2 (BN1 finalize+apply+ReLU fused into GEMM; A fp32)
  k_gemm_mfma<FH, true><<<GM, BT, 0, stream>>>(bufB, W2, stats1, gamma, beta, dis, bufA);
  k_gather<<<2048, BT, 0, stream>>>(bufA, csr, off, deg, dis, bufB, stats2);

  // fused pooling (BN2+ReLU) + final linear: one block per graph
  k_pool_final<<<NGRAPH, BT, 0, stream>>>(bufB, batch, stats2, gamma, beta, linW, linb, out);
}